// Round 9
// baseline (269.763 us; speedup 1.0000x reference)
//
#include <hip/hip_runtime.h>
#include <hip/hip_bf16.h>

#define N_NODES 2048
#define N_EDGES 32768
#define BT      128           // B*T
#define TT      16
#define CH      32
#define E2      (N_EDGES + N_NODES)

static __device__ __forceinline__ unsigned pk2(float a, float b) {
    __hip_bfloat162 h2(__float2bfloat16(a), __float2bfloat16(b));   // a -> low 16
    return *reinterpret_cast<unsigned*>(&h2);
}

// ---------------- degree + attr segment sum ----------------
__global__ void deg_attr_kernel(const int* __restrict__ ei,
                                const float* __restrict__ ea,
                                int* __restrict__ deg, float* __restrict__ asum) {
    int e = blockIdx.x * 256 + threadIdx.x;
    if (e < N_EDGES) {
        int dst = ei[N_EDGES + e];
        atomicAdd(&deg[dst], 1);
        atomicAdd(&asum[dst], ea[e]);
    }
}

// ---------------- row_ptr scan (single wave) ----------------
__global__ void scan_kernel(const int* __restrict__ deg, int* __restrict__ rowp) {
    int lane = threadIdx.x;          // 64 threads
    int base = lane * 32;
    int loc[32];
    int s = 0;
    #pragma unroll
    for (int i = 0; i < 32; ++i) { loc[i] = s; s += deg[base + i] + 1; } // +1 self loop
    int inc = s;
    #pragma unroll
    for (int d = 1; d < 64; d <<= 1) {
        int v = __shfl_up(inc, d, 64);
        if (lane >= d) inc += v;
    }
    int excl = inc - s;
    #pragma unroll
    for (int i = 0; i < 32; ++i) rowp[base + i] = excl + loc[i];
    if (lane == 63) rowp[N_NODES] = inc;
}

// ---------------- scatter edges into CSR (by dst) ----------------
__global__ void scatter_kernel(const int* __restrict__ ei,
                               const float* __restrict__ ea,
                               const int* __restrict__ deg, const float* __restrict__ asum,
                               const int* __restrict__ rowp, int* __restrict__ fill,
                               int* __restrict__ col, float* __restrict__ attr_s) {
    int e = blockIdx.x * 256 + threadIdx.x;
    if (e >= E2) return;
    int src, dst; float a;
    if (e < N_EDGES) {
        src = ei[e]; dst = ei[N_EDGES + e]; a = ea[e];
    } else {
        int n = e - N_EDGES;
        src = n; dst = n;
        a = asum[n] / fmaxf((float)deg[n], 1.0f);   // mean edge attr
    }
    int pos = atomicAdd(&fill[dst], 1);
    col[rowp[dst] + pos]    = src;
    attr_s[rowp[dst] + pos] = a;
}

// ---------------- projection: one node per block; xl transposed [n][c][bt] ----------------
__global__ __launch_bounds__(256) void proj_kernel(
        const float* __restrict__ x,
        const float* __restrict__ Wl, const float* __restrict__ bl,
        float* __restrict__ xlt) {
    __shared__ float xs[128 * 32];     // [bt][f]
    __shared__ float wl[1024];
    int n = blockIdx.x;
    int tid = threadIdx.x;
    for (int i = tid; i < 1024; i += 256) wl[i] = Wl[i];
    #pragma unroll
    for (int i = 0; i < 16; ++i) {
        int e = i * 256 + tid;
        int bt = e >> 5, f = e & 31;
        xs[e] = x[((long)bt * N_NODES + n) * 32 + f];
    }
    __syncthreads();
    int c = tid & 31;
    int btl = tid >> 5;                // 0..7
    float blc = bl[c];
    for (int i = 0; i < 16; ++i) {
        int bt = i * 8 + btl;
        float al = 0.f;
        #pragma unroll
        for (int f = 0; f < 32; ++f)
            al = fmaf(xs[bt * 32 + f], wl[f * 32 + c], al);   // broadcast + conflict-free
        xlt[((long)n * 32 + c) * 128 + bt] = al + blc;        // transposed
    }
}

// ---------------- GAT + x-side GRU gates fused (gi stored bf16) ----------------
// lane = bt; one wave = (node, 64 bt). Computes xr on the fly (uniform W -> s_load),
// aggregates with exact softmax (bounded scores, shift-invariant), then the epilogue
// computes gi = h @ wih^T + bih and stores bf16 (halves the 100MB stream that was
// thrashing L3 and forcing xlt gathers to HBM in r8: FETCH 266MB/dispatch).
__global__ __launch_bounds__(256) void gat_kernel(
        const float* __restrict__ xlt,   // [n][c][bt]
        const float* __restrict__ x,     // [bt][n][f]
        const int* __restrict__ rowp, const int* __restrict__ col,
        const float* __restrict__ attr_s,
        const float* __restrict__ Wr, const float* __restrict__ br,
        const float* __restrict__ We, const float* __restrict__ att,
        const float* __restrict__ ob,
        const float* __restrict__ wih, const float* __restrict__ bih,
        __hip_bfloat16* __restrict__ gi) {   // [bt*N+n][96] bf16
    int tid = threadIdx.x;
    int wv = tid >> 6, lane = tid & 63;
    int task = blockIdx.x * 4 + wv;      // 4096 tasks = 2048 n x 2 btg
    int n   = task >> 1;
    int bt  = ((task & 1) << 6) | lane;

    // x row for this (bt,n): per-lane contiguous 128B
    float xf[32];
    {
        const float* xp = x + ((long)bt * N_NODES + n) * 32;
        #pragma unroll
        for (int f4 = 0; f4 < 8; ++f4) {
            float4 a = *(const float4*)(xp + f4 * 4);
            xf[f4*4+0]=a.x; xf[f4*4+1]=a.y; xf[f4*4+2]=a.z; xf[f4*4+3]=a.w;
        }
    }
    // xr = x @ Wr + br  (Wr reads are wave-uniform -> scalar loads)
    float xrv[32];
    #pragma unroll
    for (int c = 0; c < 32; ++c) {
        float s = br[c];
        #pragma unroll
        for (int f = 0; f < 32; ++f) s = fmaf(xf[f], Wr[f * 32 + c], s);
        xrv[c] = s;
    }

    float accv[32];
    #pragma unroll
    for (int c = 0; c < 32; ++c) accv[c] = 0.f;

    int beg = rowp[n];
    int end = rowp[n + 1];
    float den = 0.f;
    const float* xbase = xlt + bt;
    for (int j = beg; j < end; ++j) {
        int   src = col[j];
        float av  = attr_s[j];
        const float* gp = xbase + (long)src * (CH * 128);
        float xlv[32];
        #pragma unroll
        for (int c = 0; c < 32; ++c) xlv[c] = gp[c * 128];
        float p0 = 0.f, p1 = 0.f, p2 = 0.f, p3 = 0.f;
        #pragma unroll
        for (int k = 0; k < 8; ++k) {
            { int c = k;      float m = xlv[c] + fmaf(av, We[c], xrv[c]); p0 = fmaf(att[c], fmaxf(m, 0.2f * m), p0); }
            { int c = k + 8;  float m = xlv[c] + fmaf(av, We[c], xrv[c]); p1 = fmaf(att[c], fmaxf(m, 0.2f * m), p1); }
            { int c = k + 16; float m = xlv[c] + fmaf(av, We[c], xrv[c]); p2 = fmaf(att[c], fmaxf(m, 0.2f * m), p2); }
            { int c = k + 24; float m = xlv[c] + fmaf(av, We[c], xrv[c]); p3 = fmaf(att[c], fmaxf(m, 0.2f * m), p3); }
        }
        float p = fminf((p0 + p1) + (p2 + p3), 80.f);
        float w = __expf(p);
        den += w;
        #pragma unroll
        for (int c = 0; c < 32; ++c) accv[c] = fmaf(w, xlv[c], accv[c]);
    }
    float inv = 1.f / den;
    #pragma unroll
    for (int c = 0; c < 32; ++c) accv[c] = fmaf(accv[c], inv, ob[c]);   // h

    // gi = h @ wih^T + bih ; wih reads wave-uniform -> s_load; 8 chains per 16B store
    __hip_bfloat16* gip = gi + ((long)bt * N_NODES + n) * 96;
    #pragma unroll
    for (int g8 = 0; g8 < 12; ++g8) {
        float s0 = bih[g8*8+0], s1 = bih[g8*8+1], s2 = bih[g8*8+2], s3 = bih[g8*8+3];
        float s4 = bih[g8*8+4], s5 = bih[g8*8+5], s6 = bih[g8*8+6], s7 = bih[g8*8+7];
        #pragma unroll
        for (int f = 0; f < 32; ++f) {
            float hf = accv[f];
            s0 = fmaf(hf, wih[(g8*8+0)*32+f], s0);
            s1 = fmaf(hf, wih[(g8*8+1)*32+f], s1);
            s2 = fmaf(hf, wih[(g8*8+2)*32+f], s2);
            s3 = fmaf(hf, wih[(g8*8+3)*32+f], s3);
            s4 = fmaf(hf, wih[(g8*8+4)*32+f], s4);
            s5 = fmaf(hf, wih[(g8*8+5)*32+f], s5);
            s6 = fmaf(hf, wih[(g8*8+6)*32+f], s6);
            s7 = fmaf(hf, wih[(g8*8+7)*32+f], s7);
        }
        uint4 v;
        v.x = pk2(s0, s1); v.y = pk2(s2, s3); v.z = pk2(s4, s5); v.w = pk2(s6, s7);
        *(uint4*)(gip + g8 * 8) = v;   // 8 bf16 = 16B store
    }
}

// ---------------- GRU recurrence: h-side only, 48 weights/lane, bf16 gi in ----------------
// one wave = one seq (b,n); lane = (c, fhalf): fhalf = lane>>5, c = lane&31.
__global__ __launch_bounds__(256) void gru_kernel(
        const float* __restrict__ whh, const float* __restrict__ bhh,
        const __hip_bfloat16* __restrict__ gi,   // [bt*N+n][96] bf16
        float* __restrict__ out) {               // [b,t,n,c]
    int tid  = threadIdx.x;
    int lane = tid & 63;
    int c    = lane & 31;
    int half = lane >> 5;
    int fbase = half << 4;
    int seq  = blockIdx.x * 4 + (tid >> 6);  // seq = b*2048 + n
    int b = seq >> 11;
    int n = seq & 2047;

    // 48 weights: rows {c, 32+c, 64+c} of whh, cols [fbase, fbase+16)
    float w0[16], w1[16], w2[16];
    #pragma unroll
    for (int k4 = 0; k4 < 4; ++k4) {
        float4 a0 = *(const float4*)&whh[( 0 + c) * 32 + fbase + k4 * 4];
        float4 a1 = *(const float4*)&whh[(32 + c) * 32 + fbase + k4 * 4];
        float4 a2 = *(const float4*)&whh[(64 + c) * 32 + fbase + k4 * 4];
        w0[k4*4+0]=a0.x; w0[k4*4+1]=a0.y; w0[k4*4+2]=a0.z; w0[k4*4+3]=a0.w;
        w1[k4*4+0]=a1.x; w1[k4*4+1]=a1.y; w1[k4*4+2]=a1.z; w1[k4*4+3]=a1.w;
        w2[k4*4+0]=a2.x; w2[k4*4+1]=a2.y; w2[k4*4+2]=a2.z; w2[k4*4+3]=a2.w;
    }
    float bh0 = half ? 0.f : bhh[c];        // count biases once (half0)
    float bh1 = half ? 0.f : bhh[32 + c];
    float bh2 = half ? 0.f : bhh[64 + c];

    const long GSTR = (long)N_NODES * 96;   // gi per-t stride
    long gbase = ((long)b * TT * N_NODES + n) * 96 + c;
    const long OSTR = (long)N_NODES * CH;
    long obase = ((long)b * TT * N_NODES + n) * CH + c;

    float hc = 0.f;
    float gr = __bfloat162float(gi[gbase]);
    float gz = __bfloat162float(gi[gbase + 32]);
    float gn = __bfloat162float(gi[gbase + 64]);
    #pragma unroll 1
    for (int t = 0; t < TT; ++t) {
        long gnx = gbase + (long)(t + 1) * GSTR;
        float grn = 0.f, gzn = 0.f, gnn = 0.f;
        if (t + 1 < TT) {
            grn = __bfloat162float(gi[gnx]);
            gzn = __bfloat162float(gi[gnx + 32]);
            gnn = __bfloat162float(gi[gnx + 64]);
        }
        float g0 = bh0, g1 = bh1, g2 = bh2;
        #pragma unroll
        for (int k = 0; k < 16; ++k) {
            float v = __shfl(hc, fbase + k, 64);   // h[f], sourced from half0 lanes
            g0 = fmaf(v, w0[k], g0);
            g1 = fmaf(v, w1[k], g1);
            g2 = fmaf(v, w2[k], g2);
        }
        float G0 = g0 + __shfl_xor(g0, 32, 64);    // hr + bhr  (full f-range)
        float G1 = g1 + __shfl_xor(g1, 32, 64);    // hz + bhz
        float G2 = g2 + __shfl_xor(g2, 32, 64);    // hn + bhn
        float r  = 1.f / (1.f + __expf(-(gr + G0)));
        float z  = 1.f / (1.f + __expf(-(gz + G1)));
        float a  = fmaf(r, G2, gn);
        float e2 = __expf(2.f * a);
        float nc = 1.f - 2.f / (e2 + 1.f);         // tanh, no inf/inf
        hc = (1.f - z) * nc + z * hc;
        if (half == 0) out[obase + (long)t * OSTR] = hc;   // coalesced 128B
        gr = grn; gz = gzn; gn = gnn;
    }
}

extern "C" void kernel_launch(void* const* d_in, const int* in_sizes, int n_in,
                              void* d_out, int out_size, void* d_ws, size_t ws_size,
                              hipStream_t stream) {
    const float* x    = (const float*)d_in[0];
    const int*   ei   = (const int*)d_in[1];
    const float* ea   = (const float*)d_in[2];
    const float* Wl   = (const float*)d_in[3];
    const float* bl   = (const float*)d_in[4];
    const float* Wr   = (const float*)d_in[5];
    const float* br   = (const float*)d_in[6];
    const float* We   = (const float*)d_in[7];
    const float* att  = (const float*)d_in[8];
    const float* ob   = (const float*)d_in[9];
    const float* wih  = (const float*)d_in[10];
    const float* whh  = (const float*)d_in[11];
    const float* bih  = (const float*)d_in[12];
    const float* bhh  = (const float*)d_in[13];
    float* out = (float*)d_out;

    // ---- workspace carve: small CSR metadata FIRST, then big arrays ----
    const long RB = (long)BT * N_NODES * CH;   // 8,388,608 elements
    int*   deg  = (int*)d_ws;                  // N
    float* asum = (float*)(deg + N_NODES);     // N
    int*   fill = (int*)(asum + N_NODES);      // N
    int*   rowp = fill + N_NODES;              // N+1 (padded to +16)
    int*   col  = rowp + (N_NODES + 16);       // E2
    float* attr_s = (float*)(col + E2);        // E2
    float* xlt  = (float*)(attr_s + E2);
    xlt = (float*)(((uintptr_t)xlt + 255) & ~(uintptr_t)255);
    __hip_bfloat16* gi = (__hip_bfloat16*)(xlt + RB);   // [BT*N][96] bf16 = 50.3 MB

    // zero the three counter arrays (contiguous: deg, asum, fill)
    hipMemsetAsync(deg, 0, 3 * N_NODES * sizeof(int), stream);

    deg_attr_kernel<<<N_EDGES / 256, 256, 0, stream>>>(ei, ea, deg, asum);
    scan_kernel<<<1, 64, 0, stream>>>(deg, rowp);
    scatter_kernel<<<(E2 + 255) / 256, 256, 0, stream>>>(ei, ea, deg, asum, rowp, fill, col, attr_s);
    proj_kernel<<<N_NODES, 256, 0, stream>>>(x, Wl, bl, xlt);
    gat_kernel<<<(N_NODES * 2) / 4, 256, 0, stream>>>(xlt, x, rowp, col, attr_s,
                                                      Wr, br, We, att, ob, wih, bih, gi);
    gru_kernel<<<(BT / TT * N_NODES) / 4, 256, 0, stream>>>(whh, bhh, gi, out);
}

// Round 10
// 233.612 us; speedup vs baseline: 1.1547x; 1.1547x over previous
//
#include <hip/hip_runtime.h>
#include <hip/hip_bf16.h>

#define N_NODES 2048
#define N_EDGES 32768
#define BT      128           // B*T
#define TT      16
#define CH      32
#define E2      (N_EDGES + N_NODES)

static __device__ __forceinline__ unsigned pk2(float a, float b) {
    __hip_bfloat162 h2(__float2bfloat16(a), __float2bfloat16(b));   // a -> low 16
    return *reinterpret_cast<unsigned*>(&h2);
}

// ---------------- degree + attr segment sum ----------------
__global__ void deg_attr_kernel(const int* __restrict__ ei,
                                const float* __restrict__ ea,
                                int* __restrict__ deg, float* __restrict__ asum) {
    int e = blockIdx.x * 256 + threadIdx.x;
    if (e < N_EDGES) {
        int dst = ei[N_EDGES + e];
        atomicAdd(&deg[dst], 1);
        atomicAdd(&asum[dst], ea[e]);
    }
}

// ---------------- row_ptr scan (single wave) ----------------
__global__ void scan_kernel(const int* __restrict__ deg, int* __restrict__ rowp) {
    int lane = threadIdx.x;          // 64 threads
    int base = lane * 32;
    int loc[32];
    int s = 0;
    #pragma unroll
    for (int i = 0; i < 32; ++i) { loc[i] = s; s += deg[base + i] + 1; } // +1 self loop
    int inc = s;
    #pragma unroll
    for (int d = 1; d < 64; d <<= 1) {
        int v = __shfl_up(inc, d, 64);
        if (lane >= d) inc += v;
    }
    int excl = inc - s;
    #pragma unroll
    for (int i = 0; i < 32; ++i) rowp[base + i] = excl + loc[i];
    if (lane == 63) rowp[N_NODES] = inc;
}

// ---------------- scatter edges into CSR (by dst) ----------------
__global__ void scatter_kernel(const int* __restrict__ ei,
                               const float* __restrict__ ea,
                               const int* __restrict__ deg, const float* __restrict__ asum,
                               const int* __restrict__ rowp, int* __restrict__ fill,
                               int* __restrict__ col, float* __restrict__ attr_s) {
    int e = blockIdx.x * 256 + threadIdx.x;
    if (e >= E2) return;
    int src, dst; float a;
    if (e < N_EDGES) {
        src = ei[e]; dst = ei[N_EDGES + e]; a = ea[e];
    } else {
        int n = e - N_EDGES;
        src = n; dst = n;
        a = asum[n] / fmaxf((float)deg[n], 1.0f);   // mean edge attr
    }
    int pos = atomicAdd(&fill[dst], 1);
    col[rowp[dst] + pos]    = src;
    attr_s[rowp[dst] + pos] = a;
}

// ---------------- projection: one node per block; xl -> packed bf16x2 [n][16][128] ----------------
__global__ __launch_bounds__(256) void proj_kernel(
        const float* __restrict__ x,
        const float* __restrict__ Wl, const float* __restrict__ bl,
        unsigned* __restrict__ xlt) {      // [n][c2][bt] packed (2 channels / dword)
    __shared__ float xs[128 * 32];     // [bt][f]
    __shared__ float wl[1024];
    int n = blockIdx.x;
    int tid = threadIdx.x;
    for (int i = tid; i < 1024; i += 256) wl[i] = Wl[i];
    #pragma unroll
    for (int i = 0; i < 16; ++i) {
        int e = i * 256 + tid;
        int bt = e >> 5, f = e & 31;
        xs[e] = x[((long)bt * N_NODES + n) * 32 + f];
    }
    __syncthreads();
    int c2  = tid & 15;                // lanes share bt -> xs reads broadcast
    int btl = tid >> 4;                // 0..15
    int c0 = 2 * c2, c1 = c0 + 1;
    float b0 = bl[c0], b1 = bl[c1];
    for (int i = 0; i < 8; ++i) {
        int bt = i * 16 + btl;
        float a0 = 0.f, a1 = 0.f;
        #pragma unroll
        for (int f = 0; f < 32; ++f) {
            float xv = xs[bt * 32 + f];           // broadcast read
            a0 = fmaf(xv, wl[f * 32 + c0], a0);
            a1 = fmaf(xv, wl[f * 32 + c1], a1);
        }
        xlt[((long)n * 16 + c2) * 128 + bt] = pk2(a0 + b0, a1 + b1);
    }
}

// ---------------- GAT + x-side GRU gates fused (bf16-packed gathers, bf16 gi out) ----------------
// lane = bt; one wave = (node, 64 bt). Gather: 16 dword loads/edge (2 bf16 ch each),
// halving both L2-miss bytes and load-issue count vs f32 (r9: FETCH 263MB, gather-bound).
__global__ __launch_bounds__(256) void gat_kernel(
        const unsigned* __restrict__ xlt,   // [n][16][128] packed bf16x2
        const float* __restrict__ x,        // [bt][n][f]
        const int* __restrict__ rowp, const int* __restrict__ col,
        const float* __restrict__ attr_s,
        const float* __restrict__ Wr, const float* __restrict__ br,
        const float* __restrict__ We, const float* __restrict__ att,
        const float* __restrict__ ob,
        const float* __restrict__ wih, const float* __restrict__ bih,
        __hip_bfloat16* __restrict__ gi) {   // [bt*N+n][96] bf16
    int tid = threadIdx.x;
    int wv = tid >> 6, lane = tid & 63;
    int task = blockIdx.x * 4 + wv;      // 4096 tasks = 2048 n x 2 btg
    int n   = task >> 1;
    int bt  = ((task & 1) << 6) | lane;

    // x row for this (bt,n): per-lane contiguous 128B
    float xf[32];
    {
        const float* xp = x + ((long)bt * N_NODES + n) * 32;
        #pragma unroll
        for (int f4 = 0; f4 < 8; ++f4) {
            float4 a = *(const float4*)(xp + f4 * 4);
            xf[f4*4+0]=a.x; xf[f4*4+1]=a.y; xf[f4*4+2]=a.z; xf[f4*4+3]=a.w;
        }
    }
    // xr = x @ Wr + br  (Wr reads are wave-uniform -> scalar loads)
    float xrv[32];
    #pragma unroll
    for (int c = 0; c < 32; ++c) {
        float s = br[c];
        #pragma unroll
        for (int f = 0; f < 32; ++f) s = fmaf(xf[f], Wr[f * 32 + c], s);
        xrv[c] = s;
    }

    float accv[32];
    #pragma unroll
    for (int c = 0; c < 32; ++c) accv[c] = 0.f;

    int beg = rowp[n];
    int end = rowp[n + 1];
    float den = 0.f;
    const unsigned* xbase = xlt + bt;
    for (int j = beg; j < end; ++j) {
        int   src = col[j];
        float av  = attr_s[j];
        const unsigned* gp = xbase + (long)src * (16 * 128);
        float xlv[32];
        #pragma unroll
        for (int c2 = 0; c2 < 16; ++c2) {
            unsigned u = gp[c2 * 128];
            xlv[2*c2]   = __uint_as_float(u << 16);          // low bf16 -> f32
            xlv[2*c2+1] = __uint_as_float(u & 0xffff0000u);  // high bf16 -> f32
        }
        float p0 = 0.f, p1 = 0.f, p2 = 0.f, p3 = 0.f;
        #pragma unroll
        for (int k = 0; k < 8; ++k) {
            { int c = k;      float m = xlv[c] + fmaf(av, We[c], xrv[c]); p0 = fmaf(att[c], fmaxf(m, 0.2f * m), p0); }
            { int c = k + 8;  float m = xlv[c] + fmaf(av, We[c], xrv[c]); p1 = fmaf(att[c], fmaxf(m, 0.2f * m), p1); }
            { int c = k + 16; float m = xlv[c] + fmaf(av, We[c], xrv[c]); p2 = fmaf(att[c], fmaxf(m, 0.2f * m), p2); }
            { int c = k + 24; float m = xlv[c] + fmaf(av, We[c], xrv[c]); p3 = fmaf(att[c], fmaxf(m, 0.2f * m), p3); }
        }
        // scores bounded; softmax shift-invariant -> no max subtraction. Clamp = insurance.
        float p = fminf((p0 + p1) + (p2 + p3), 80.f);
        float w = __expf(p);
        den += w;
        #pragma unroll
        for (int c = 0; c < 32; ++c) accv[c] = fmaf(w, xlv[c], accv[c]);
    }
    float inv = 1.f / den;
    #pragma unroll
    for (int c = 0; c < 32; ++c) accv[c] = fmaf(accv[c], inv, ob[c]);   // h

    // gi = h @ wih^T + bih ; wih reads wave-uniform -> s_load; 8 chains per 16B store
    __hip_bfloat16* gip = gi + ((long)bt * N_NODES + n) * 96;
    #pragma unroll
    for (int g8 = 0; g8 < 12; ++g8) {
        float s0 = bih[g8*8+0], s1 = bih[g8*8+1], s2 = bih[g8*8+2], s3 = bih[g8*8+3];
        float s4 = bih[g8*8+4], s5 = bih[g8*8+5], s6 = bih[g8*8+6], s7 = bih[g8*8+7];
        #pragma unroll
        for (int f = 0; f < 32; ++f) {
            float hf = accv[f];
            s0 = fmaf(hf, wih[(g8*8+0)*32+f], s0);
            s1 = fmaf(hf, wih[(g8*8+1)*32+f], s1);
            s2 = fmaf(hf, wih[(g8*8+2)*32+f], s2);
            s3 = fmaf(hf, wih[(g8*8+3)*32+f], s3);
            s4 = fmaf(hf, wih[(g8*8+4)*32+f], s4);
            s5 = fmaf(hf, wih[(g8*8+5)*32+f], s5);
            s6 = fmaf(hf, wih[(g8*8+6)*32+f], s6);
            s7 = fmaf(hf, wih[(g8*8+7)*32+f], s7);
        }
        uint4 v;
        v.x = pk2(s0, s1); v.y = pk2(s2, s3); v.z = pk2(s4, s5); v.w = pk2(s6, s7);
        *(uint4*)(gip + g8 * 8) = v;   // 8 bf16 = 16B store
    }
}

// ---------------- GRU recurrence: h-side only, 48 weights/lane, bf16 gi in ----------------
// one wave = one seq (b,n); lane = (c, fhalf): fhalf = lane>>5, c = lane&31.
__global__ __launch_bounds__(256) void gru_kernel(
        const float* __restrict__ whh, const float* __restrict__ bhh,
        const __hip_bfloat16* __restrict__ gi,   // [bt*N+n][96] bf16
        float* __restrict__ out) {               // [b,t,n,c]
    int tid  = threadIdx.x;
    int lane = tid & 63;
    int c    = lane & 31;
    int half = lane >> 5;
    int fbase = half << 4;
    int seq  = blockIdx.x * 4 + (tid >> 6);  // seq = b*2048 + n
    int b = seq >> 11;
    int n = seq & 2047;

    // 48 weights: rows {c, 32+c, 64+c} of whh, cols [fbase, fbase+16)
    float w0[16], w1[16], w2[16];
    #pragma unroll
    for (int k4 = 0; k4 < 4; ++k4) {
        float4 a0 = *(const float4*)&whh[( 0 + c) * 32 + fbase + k4 * 4];
        float4 a1 = *(const float4*)&whh[(32 + c) * 32 + fbase + k4 * 4];
        float4 a2 = *(const float4*)&whh[(64 + c) * 32 + fbase + k4 * 4];
        w0[k4*4+0]=a0.x; w0[k4*4+1]=a0.y; w0[k4*4+2]=a0.z; w0[k4*4+3]=a0.w;
        w1[k4*4+0]=a1.x; w1[k4*4+1]=a1.y; w1[k4*4+2]=a1.z; w1[k4*4+3]=a1.w;
        w2[k4*4+0]=a2.x; w2[k4*4+1]=a2.y; w2[k4*4+2]=a2.z; w2[k4*4+3]=a2.w;
    }
    float bh0 = half ? 0.f : bhh[c];        // count biases once (half0)
    float bh1 = half ? 0.f : bhh[32 + c];
    float bh2 = half ? 0.f : bhh[64 + c];

    const long GSTR = (long)N_NODES * 96;   // gi per-t stride
    long gbase = ((long)b * TT * N_NODES + n) * 96 + c;
    const long OSTR = (long)N_NODES * CH;
    long obase = ((long)b * TT * N_NODES + n) * CH + c;

    float hc = 0.f;
    float gr = __bfloat162float(gi[gbase]);
    float gz = __bfloat162float(gi[gbase + 32]);
    float gn = __bfloat162float(gi[gbase + 64]);
    #pragma unroll 1
    for (int t = 0; t < TT; ++t) {
        long gnx = gbase + (long)(t + 1) * GSTR;
        float grn = 0.f, gzn = 0.f, gnn = 0.f;
        if (t + 1 < TT) {
            grn = __bfloat162float(gi[gnx]);
            gzn = __bfloat162float(gi[gnx + 32]);
            gnn = __bfloat162float(gi[gnx + 64]);
        }
        float g0 = bh0, g1 = bh1, g2 = bh2;
        #pragma unroll
        for (int k = 0; k < 16; ++k) {
            float v = __shfl(hc, fbase + k, 64);   // h[f], sourced from half0 lanes
            g0 = fmaf(v, w0[k], g0);
            g1 = fmaf(v, w1[k], g1);
            g2 = fmaf(v, w2[k], g2);
        }
        float G0 = g0 + __shfl_xor(g0, 32, 64);    // hr + bhr  (full f-range)
        float G1 = g1 + __shfl_xor(g1, 32, 64);    // hz + bhz
        float G2 = g2 + __shfl_xor(g2, 32, 64);    // hn + bhn
        float r  = 1.f / (1.f + __expf(-(gr + G0)));
        float z  = 1.f / (1.f + __expf(-(gz + G1)));
        float a  = fmaf(r, G2, gn);
        float e2 = __expf(2.f * a);
        float nc = 1.f - 2.f / (e2 + 1.f);         // tanh, no inf/inf
        hc = (1.f - z) * nc + z * hc;
        if (half == 0) out[obase + (long)t * OSTR] = hc;   // coalesced 128B
        gr = grn; gz = gzn; gn = gnn;
    }
}

extern "C" void kernel_launch(void* const* d_in, const int* in_sizes, int n_in,
                              void* d_out, int out_size, void* d_ws, size_t ws_size,
                              hipStream_t stream) {
    const float* x    = (const float*)d_in[0];
    const int*   ei   = (const int*)d_in[1];
    const float* ea   = (const float*)d_in[2];
    const float* Wl   = (const float*)d_in[3];
    const float* bl   = (const float*)d_in[4];
    const float* Wr   = (const float*)d_in[5];
    const float* br   = (const float*)d_in[6];
    const float* We   = (const float*)d_in[7];
    const float* att  = (const float*)d_in[8];
    const float* ob   = (const float*)d_in[9];
    const float* wih  = (const float*)d_in[10];
    const float* whh  = (const float*)d_in[11];
    const float* bih  = (const float*)d_in[12];
    const float* bhh  = (const float*)d_in[13];
    float* out = (float*)d_out;

    // ---- workspace carve: small CSR metadata FIRST, then big arrays ----
    int*   deg  = (int*)d_ws;                  // N
    float* asum = (float*)(deg + N_NODES);     // N
    int*   fill = (int*)(asum + N_NODES);      // N
    int*   rowp = fill + N_NODES;              // N+1 (padded to +16)
    int*   col  = rowp + (N_NODES + 16);       // E2
    float* attr_s = (float*)(col + E2);        // E2
    unsigned* xlt = (unsigned*)(attr_s + E2);  // [N][16][128] packed = 16.8 MB
    xlt = (unsigned*)(((uintptr_t)xlt + 255) & ~(uintptr_t)255);
    __hip_bfloat16* gi = (__hip_bfloat16*)(xlt + (long)N_NODES * 16 * 128);  // 50.3 MB

    // zero the three counter arrays (contiguous: deg, asum, fill)
    hipMemsetAsync(deg, 0, 3 * N_NODES * sizeof(int), stream);

    deg_attr_kernel<<<N_EDGES / 256, 256, 0, stream>>>(ei, ea, deg, asum);
    scan_kernel<<<1, 64, 0, stream>>>(deg, rowp);
    scatter_kernel<<<(E2 + 255) / 256, 256, 0, stream>>>(ei, ea, deg, asum, rowp, fill, col, attr_s);
    proj_kernel<<<N_NODES, 256, 0, stream>>>(x, Wl, bl, xlt);
    gat_kernel<<<(N_NODES * 2) / 4, 256, 0, stream>>>(xlt, x, rowp, col, attr_s,
                                                      Wr, br, We, att, ob, wih, bih, gi);
    gru_kernel<<<(BT / TT * N_NODES) / 4, 256, 0, stream>>>(whh, bhh, gi, out);
}

// Round 11
// 231.587 us; speedup vs baseline: 1.1648x; 1.0087x over previous
//
#include <hip/hip_runtime.h>
#include <hip/hip_bf16.h>

#define N_NODES 2048
#define N_EDGES 32768
#define BT      128           // B*T
#define TT      16
#define CH      32
#define E2      (N_EDGES + N_NODES)

static __device__ __forceinline__ unsigned pk2(float a, float b) {
    __hip_bfloat162 h2(__float2bfloat16(a), __float2bfloat16(b));   // a -> low 16
    return *reinterpret_cast<unsigned*>(&h2);
}

// ---------------- degree + attr segment sum ----------------
__global__ void deg_attr_kernel(const int* __restrict__ ei,
                                const float* __restrict__ ea,
                                int* __restrict__ deg, float* __restrict__ asum) {
    int e = blockIdx.x * 256 + threadIdx.x;
    if (e < N_EDGES) {
        int dst = ei[N_EDGES + e];
        atomicAdd(&deg[dst], 1);
        atomicAdd(&asum[dst], ea[e]);
    }
}

// ---------------- row_ptr scan (single wave) ----------------
__global__ void scan_kernel(const int* __restrict__ deg, int* __restrict__ rowp) {
    int lane = threadIdx.x;          // 64 threads
    int base = lane * 32;
    int loc[32];
    int s = 0;
    #pragma unroll
    for (int i = 0; i < 32; ++i) { loc[i] = s; s += deg[base + i] + 1; } // +1 self loop
    int inc = s;
    #pragma unroll
    for (int d = 1; d < 64; d <<= 1) {
        int v = __shfl_up(inc, d, 64);
        if (lane >= d) inc += v;
    }
    int excl = inc - s;
    #pragma unroll
    for (int i = 0; i < 32; ++i) rowp[base + i] = excl + loc[i];
    if (lane == 63) rowp[N_NODES] = inc;
}

// ---------------- scatter edges into CSR (by dst) ----------------
__global__ void scatter_kernel(const int* __restrict__ ei,
                               const float* __restrict__ ea,
                               const int* __restrict__ deg, const float* __restrict__ asum,
                               const int* __restrict__ rowp, int* __restrict__ fill,
                               int* __restrict__ col, float* __restrict__ attr_s) {
    int e = blockIdx.x * 256 + threadIdx.x;
    if (e >= E2) return;
    int src, dst; float a;
    if (e < N_EDGES) {
        src = ei[e]; dst = ei[N_EDGES + e]; a = ea[e];
    } else {
        int n = e - N_EDGES;
        src = n; dst = n;
        a = asum[n] / fmaxf((float)deg[n], 1.0f);   // mean edge attr
    }
    int pos = atomicAdd(&fill[dst], 1);
    col[rowp[dst] + pos]    = src;
    attr_s[rowp[dst] + pos] = a;
}

// ---------------- projection: one node per block; xl -> packed bf16x2 [n][16][128] ----------------
__global__ __launch_bounds__(256) void proj_kernel(
        const float* __restrict__ x,
        const float* __restrict__ Wl, const float* __restrict__ bl,
        unsigned* __restrict__ xlt) {      // [n][c2][bt] packed (2 channels / dword)
    __shared__ float xs[128 * 32];     // [bt][f]
    __shared__ float wl[1024];
    int n = blockIdx.x;
    int tid = threadIdx.x;
    for (int i = tid; i < 1024; i += 256) wl[i] = Wl[i];
    #pragma unroll
    for (int i = 0; i < 16; ++i) {
        int e = i * 256 + tid;
        int bt = e >> 5, f = e & 31;
        xs[e] = x[((long)bt * N_NODES + n) * 32 + f];
    }
    __syncthreads();
    int c2  = tid & 15;                // lanes share bt -> xs reads broadcast
    int btl = tid >> 4;                // 0..15
    int c0 = 2 * c2, c1 = c0 + 1;
    float b0 = bl[c0], b1 = bl[c1];
    for (int i = 0; i < 8; ++i) {
        int bt = i * 16 + btl;
        float a0 = 0.f, a1 = 0.f;
        #pragma unroll
        for (int f = 0; f < 32; ++f) {
            float xv = xs[bt * 32 + f];           // broadcast read
            a0 = fmaf(xv, wl[f * 32 + c0], a0);
            a1 = fmaf(xv, wl[f * 32 + c1], a1);
        }
        xlt[((long)n * 16 + c2) * 128 + bt] = pk2(a0 + b0, a1 + b1);
    }
}

// ---------------- GAT + x-side GRU gates fused; 2-stage prefetch edge loop ----------------
// lane = bt; one wave = (node, 64 bt). Edge loop is software-pipelined: edge j+1's 16
// packed dwords + col/attr are issued BEFORE edge j's compute consumes its data, hiding
// the ~500cy L2-miss latency under ~260 VALU ops (r10: latency-exposed, VALUBusy 42%).
// Edge data stays packed (16 regs) and is unpacked twice to keep VGPR < 128 (r4-r7:
// >128 live floats triggers AGPR parking + per-use copies).
__global__ __launch_bounds__(256) void gat_kernel(
        const unsigned* __restrict__ xlt,   // [n][16][128] packed bf16x2
        const float* __restrict__ x,        // [bt][n][f]
        const int* __restrict__ rowp, const int* __restrict__ col,
        const float* __restrict__ attr_s,
        const float* __restrict__ Wr, const float* __restrict__ br,
        const float* __restrict__ We, const float* __restrict__ att,
        const float* __restrict__ ob,
        const float* __restrict__ wih, const float* __restrict__ bih,
        __hip_bfloat16* __restrict__ gi) {   // [bt*N+n][96] bf16
    int tid = threadIdx.x;
    int wv = tid >> 6, lane = tid & 63;
    int task = blockIdx.x * 4 + wv;      // 4096 tasks = 2048 n x 2 btg
    int n   = task >> 1;
    int bt  = ((task & 1) << 6) | lane;

    // x row for this (bt,n): per-lane contiguous 128B
    float xf[32];
    {
        const float* xp = x + ((long)bt * N_NODES + n) * 32;
        #pragma unroll
        for (int f4 = 0; f4 < 8; ++f4) {
            float4 a = *(const float4*)(xp + f4 * 4);
            xf[f4*4+0]=a.x; xf[f4*4+1]=a.y; xf[f4*4+2]=a.z; xf[f4*4+3]=a.w;
        }
    }
    // xr = x @ Wr + br  (Wr reads are wave-uniform -> scalar loads)
    float xrv[32];
    #pragma unroll
    for (int c = 0; c < 32; ++c) {
        float s = br[c];
        #pragma unroll
        for (int f = 0; f < 32; ++f) s = fmaf(xf[f], Wr[f * 32 + c], s);
        xrv[c] = s;
    }

    float accv[32];
    #pragma unroll
    for (int c = 0; c < 32; ++c) accv[c] = 0.f;

    int beg = rowp[n];
    int end = rowp[n + 1];           // deg >= 1 always (self loop)
    float den = 0.f;
    const unsigned* xbase = xlt + bt;

    // prologue: load edge `beg`
    unsigned up[16];
    float avp = attr_s[beg];
    {
        const unsigned* gp = xbase + (long)col[beg] * (16 * 128);
        #pragma unroll
        for (int c2 = 0; c2 < 16; ++c2) up[c2] = gp[c2 * 128];
    }

    for (int j = beg; j < end; ++j) {
        // prefetch edge j+1 (clamped: last iter re-reads j, harmless)
        int jn = (j + 1 < end) ? (j + 1) : j;
        float avn = attr_s[jn];
        unsigned un[16];
        {
            const unsigned* gp = xbase + (long)col[jn] * (16 * 128);
            #pragma unroll
            for (int c2 = 0; c2 < 16; ++c2) un[c2] = gp[c2 * 128];
        }

        // score from packed data (unpack on the fly)
        float av = avp;
        float p0 = 0.f, p1 = 0.f, p2 = 0.f, p3 = 0.f;
        #pragma unroll
        for (int c2 = 0; c2 < 16; ++c2) {
            unsigned u = up[c2];
            float x0 = __uint_as_float(u << 16);
            float x1 = __uint_as_float(u & 0xffff0000u);
            int c = 2 * c2;
            float m0 = x0 + fmaf(av, We[c],     xrv[c]);
            float m1 = x1 + fmaf(av, We[c + 1], xrv[c + 1]);
            if (c2 & 1) { p2 = fmaf(att[c], fmaxf(m0, 0.2f * m0), p2);
                          p3 = fmaf(att[c + 1], fmaxf(m1, 0.2f * m1), p3); }
            else        { p0 = fmaf(att[c], fmaxf(m0, 0.2f * m0), p0);
                          p1 = fmaf(att[c + 1], fmaxf(m1, 0.2f * m1), p1); }
        }
        // scores bounded; softmax shift-invariant -> no max subtraction. Clamp = insurance.
        float p = fminf((p0 + p1) + (p2 + p3), 80.f);
        float w = __expf(p);
        den += w;
        #pragma unroll
        for (int c2 = 0; c2 < 16; ++c2) {
            unsigned u = up[c2];
            accv[2*c2]   = fmaf(w, __uint_as_float(u << 16),         accv[2*c2]);
            accv[2*c2+1] = fmaf(w, __uint_as_float(u & 0xffff0000u), accv[2*c2+1]);
        }
        // rotate pipeline regs
        #pragma unroll
        for (int c2 = 0; c2 < 16; ++c2) up[c2] = un[c2];
        avp = avn;
    }
    float inv = 1.f / den;
    #pragma unroll
    for (int c = 0; c < 32; ++c) accv[c] = fmaf(accv[c], inv, ob[c]);   // h

    // gi = h @ wih^T + bih ; wih reads wave-uniform -> s_load; 8 chains per 16B store
    __hip_bfloat16* gip = gi + ((long)bt * N_NODES + n) * 96;
    #pragma unroll
    for (int g8 = 0; g8 < 12; ++g8) {
        float s0 = bih[g8*8+0], s1 = bih[g8*8+1], s2 = bih[g8*8+2], s3 = bih[g8*8+3];
        float s4 = bih[g8*8+4], s5 = bih[g8*8+5], s6 = bih[g8*8+6], s7 = bih[g8*8+7];
        #pragma unroll
        for (int f = 0; f < 32; ++f) {
            float hf = accv[f];
            s0 = fmaf(hf, wih[(g8*8+0)*32+f], s0);
            s1 = fmaf(hf, wih[(g8*8+1)*32+f], s1);
            s2 = fmaf(hf, wih[(g8*8+2)*32+f], s2);
            s3 = fmaf(hf, wih[(g8*8+3)*32+f], s3);
            s4 = fmaf(hf, wih[(g8*8+4)*32+f], s4);
            s5 = fmaf(hf, wih[(g8*8+5)*32+f], s5);
            s6 = fmaf(hf, wih[(g8*8+6)*32+f], s6);
            s7 = fmaf(hf, wih[(g8*8+7)*32+f], s7);
        }
        uint4 v;
        v.x = pk2(s0, s1); v.y = pk2(s2, s3); v.z = pk2(s4, s5); v.w = pk2(s6, s7);
        *(uint4*)(gip + g8 * 8) = v;   // 8 bf16 = 16B store
    }
}

// ---------------- GRU recurrence: h-side only, 48 weights/lane, bf16 gi in ----------------
// one wave = one seq (b,n); lane = (c, fhalf): fhalf = lane>>5, c = lane&31.
__global__ __launch_bounds__(256) void gru_kernel(
        const float* __restrict__ whh, const float* __restrict__ bhh,
        const __hip_bfloat16* __restrict__ gi,   // [bt*N+n][96] bf16
        float* __restrict__ out) {               // [b,t,n,c]
    int tid  = threadIdx.x;
    int lane = tid & 63;
    int c    = lane & 31;
    int half = lane >> 5;
    int fbase = half << 4;
    int seq  = blockIdx.x * 4 + (tid >> 6);  // seq = b*2048 + n
    int b = seq >> 11;
    int n = seq & 2047;

    // 48 weights: rows {c, 32+c, 64+c} of whh, cols [fbase, fbase+16)
    float w0[16], w1[16], w2[16];
    #pragma unroll
    for (int k4 = 0; k4 < 4; ++k4) {
        float4 a0 = *(const float4*)&whh[( 0 + c) * 32 + fbase + k4 * 4];
        float4 a1 = *(const float4*)&whh[(32 + c) * 32 + fbase + k4 * 4];
        float4 a2 = *(const float4*)&whh[(64 + c) * 32 + fbase + k4 * 4];
        w0[k4*4+0]=a0.x; w0[k4*4+1]=a0.y; w0[k4*4+2]=a0.z; w0[k4*4+3]=a0.w;
        w1[k4*4+0]=a1.x; w1[k4*4+1]=a1.y; w1[k4*4+2]=a1.z; w1[k4*4+3]=a1.w;
        w2[k4*4+0]=a2.x; w2[k4*4+1]=a2.y; w2[k4*4+2]=a2.z; w2[k4*4+3]=a2.w;
    }
    float bh0 = half ? 0.f : bhh[c];        // count biases once (half0)
    float bh1 = half ? 0.f : bhh[32 + c];
    float bh2 = half ? 0.f : bhh[64 + c];

    const long GSTR = (long)N_NODES * 96;   // gi per-t stride
    long gbase = ((long)b * TT * N_NODES + n) * 96 + c;
    const long OSTR = (long)N_NODES * CH;
    long obase = ((long)b * TT * N_NODES + n) * CH + c;

    float hc = 0.f;
    float gr = __bfloat162float(gi[gbase]);
    float gz = __bfloat162float(gi[gbase + 32]);
    float gn = __bfloat162float(gi[gbase + 64]);
    #pragma unroll 1
    for (int t = 0; t < TT; ++t) {
        long gnx = gbase + (long)(t + 1) * GSTR;
        float grn = 0.f, gzn = 0.f, gnn = 0.f;
        if (t + 1 < TT) {
            grn = __bfloat162float(gi[gnx]);
            gzn = __bfloat162float(gi[gnx + 32]);
            gnn = __bfloat162float(gi[gnx + 64]);
        }
        float g0 = bh0, g1 = bh1, g2 = bh2;
        #pragma unroll
        for (int k = 0; k < 16; ++k) {
            float v = __shfl(hc, fbase + k, 64);   // h[f], sourced from half0 lanes
            g0 = fmaf(v, w0[k], g0);
            g1 = fmaf(v, w1[k], g1);
            g2 = fmaf(v, w2[k], g2);
        }
        float G0 = g0 + __shfl_xor(g0, 32, 64);    // hr + bhr  (full f-range)
        float G1 = g1 + __shfl_xor(g1, 32, 64);    // hz + bhz
        float G2 = g2 + __shfl_xor(g2, 32, 64);    // hn + bhn
        float r  = 1.f / (1.f + __expf(-(gr + G0)));
        float z  = 1.f / (1.f + __expf(-(gz + G1)));
        float a  = fmaf(r, G2, gn);
        float e2 = __expf(2.f * a);
        float nc = 1.f - 2.f / (e2 + 1.f);         // tanh, no inf/inf
        hc = (1.f - z) * nc + z * hc;
        if (half == 0) out[obase + (long)t * OSTR] = hc;   // coalesced 128B
        gr = grn; gz = gzn; gn = gnn;
    }
}

extern "C" void kernel_launch(void* const* d_in, const int* in_sizes, int n_in,
                              void* d_out, int out_size, void* d_ws, size_t ws_size,
                              hipStream_t stream) {
    const float* x    = (const float*)d_in[0];
    const int*   ei   = (const int*)d_in[1];
    const float* ea   = (const float*)d_in[2];
    const float* Wl   = (const float*)d_in[3];
    const float* bl   = (const float*)d_in[4];
    const float* Wr   = (const float*)d_in[5];
    const float* br   = (const float*)d_in[6];
    const float* We   = (const float*)d_in[7];
    const float* att  = (const float*)d_in[8];
    const float* ob   = (const float*)d_in[9];
    const float* wih  = (const float*)d_in[10];
    const float* whh  = (const float*)d_in[11];
    const float* bih  = (const float*)d_in[12];
    const float* bhh  = (const float*)d_in[13];
    float* out = (float*)d_out;

    // ---- workspace carve: small CSR metadata FIRST, then big arrays ----
    int*   deg  = (int*)d_ws;                  // N
    float* asum = (float*)(deg + N_NODES);     // N
    int*   fill = (int*)(asum + N_NODES);      // N
    int*   rowp = fill + N_NODES;              // N+1 (padded to +16)
    int*   col  = rowp + (N_NODES + 16);       // E2
    float* attr_s = (float*)(col + E2);        // E2
    unsigned* xlt = (unsigned*)(attr_s + E2);  // [N][16][128] packed = 16.8 MB
    xlt = (unsigned*)(((uintptr_t)xlt + 255) & ~(uintptr_t)255);
    __hip_bfloat16* gi = (__hip_bfloat16*)(xlt + (long)N_NODES * 16 * 128);  // 50.3 MB

    // zero the three counter arrays (contiguous: deg, asum, fill)
    hipMemsetAsync(deg, 0, 3 * N_NODES * sizeof(int), stream);

    deg_attr_kernel<<<N_EDGES / 256, 256, 0, stream>>>(ei, ea, deg, asum);
    scan_kernel<<<1, 64, 0, stream>>>(deg, rowp);
    scatter_kernel<<<(E2 + 255) / 256, 256, 0, stream>>>(ei, ea, deg, asum, rowp, fill, col, attr_s);
    proj_kernel<<<N_NODES, 256, 0, stream>>>(x, Wl, bl, xlt);
    gat_kernel<<<(N_NODES * 2) / 4, 256, 0, stream>>>(xlt, x, rowp, col, attr_s,
                                                      Wr, br, We, att, ob, wih, bih, gi);
    gru_kernel<<<(BT / TT * N_NODES) / 4, 256, 0, stream>>>(whh, bhh, gi, out);
}